// Round 1
// baseline (2259.418 us; speedup 1.0000x reference)
//
#include <hip/hip_runtime.h>
#include <math.h>

#define RL(x) __builtin_amdgcn_readfirstlane(x)

__device__ __forceinline__ float relu_(float v) { return v > 0.f ? v : 0.f; }

// ---------------------------------------------------------------------------
// One-time: tiled transposes of enc_w1 [256x4096], enc_lin_w [256x256],
// dec_lin_w [128x128] into column-major copies (out[c*R + r] = in[r*C + c]).
// ---------------------------------------------------------------------------
__global__ __launch_bounds__(256) void k_transpose(
    const float* __restrict__ w1, const float* __restrict__ linw,
    const float* __restrict__ dlinw, float* __restrict__ w1T,
    float* __restrict__ linT, float* __restrict__ dlinT)
{
  __shared__ float buf[64 * 65];
  int bid = blockIdx.x;
  const float* in; float* out; int R, C, tr, tc;
  if (bid < 256)      { in = w1;    out = w1T;   R = 256; C = 4096; tr = bid >> 6;        tc = bid & 63; }
  else if (bid < 272) { in = linw;  out = linT;  R = 256; C = 256;  tr = (bid - 256) >> 2; tc = (bid - 256) & 3; }
  else                { in = dlinw; out = dlinT; R = 128; C = 128;  tr = (bid - 272) >> 1; tc = (bid - 272) & 1; }
  int r0 = tr * 64, c0 = tc * 64;
  int lane = threadIdx.x & 63, grp = threadIdx.x >> 6;
  for (int pp = 0; pp < 16; ++pp) {
    int rr = pp * 4 + grp;
    buf[rr * 65 + lane] = in[(r0 + rr) * C + c0 + lane];
  }
  __syncthreads();
  for (int pp = 0; pp < 16; ++pp) {
    int cc = pp * 4 + grp;
    out[(c0 + cc) * R + r0 + lane] = buf[lane * 65 + cc];
  }
}

// ---------------------------------------------------------------------------
// One-time: |emb_k|^2
// ---------------------------------------------------------------------------
__global__ __launch_bounds__(256) void k_embsq(const float* __restrict__ emb,
                                               float* __restrict__ embsq)
{
  int k = blockIdx.x * 256 + threadIdx.x;   // grid 2 -> 512
  const float* e = emb + k * 64;
  float s0 = 0, s1 = 0, s2 = 0, s3 = 0;
  #pragma unroll
  for (int c = 0; c < 64; c += 4) {
    s0 += e[c] * e[c]; s1 += e[c+1] * e[c+1];
    s2 += e[c+2] * e[c+2]; s3 += e[c+3] * e[c+3];
  }
  embsq[k] = (s0 + s1) + (s2 + s3);
}

// ---------------------------------------------------------------------------
// Encoder h1 step (conv fused) + (optional) fused h2-epilogue for step t-1.
// ep: 0 = none, 1 = first (h2 = relu(contract)), 2 = normal (with lin rec)
// ---------------------------------------------------------------------------
__global__ __launch_bounds__(256) void k_enc_h1(
    const float* __restrict__ x, int t,
    const float* __restrict__ w0, const float* __restrict__ w0b,
    const float* __restrict__ r0, const float* __restrict__ r0b,
    const float* __restrict__ h1_in, float* __restrict__ h1_out, int rec,
    const float* __restrict__ parts, const float* __restrict__ w1b,
    const float* __restrict__ linT, const float* __restrict__ linb,
    const float* __restrict__ h2_in, float* __restrict__ h2_out, int ep)
{
  int b = blockIdx.x, tid = threadIdx.x;
  if (ep) {  // h2 epilogue for previous step (split-K reduce + recurrence)
    int o = tid;
    float s = w1b[o];
    const float* pp = parts + b * 256 + o;
    #pragma unroll
    for (int ks = 0; ks < 16; ++ks) s += pp[ks * 65536];
    float h2h = relu_(s);
    if (ep == 2) {
      const float* h2r = h2_in + b * 256;
      float a0 = 0, a1 = 0;
      for (int j = 0; j < 256; j += 2) {
        a0 += linT[j * 256 + o] * h2r[j];
        a1 += linT[(j + 1) * 256 + o] * h2r[j + 1];
      }
      h2h = relu_(h2h + a0 + a1 + linb[o]);
    }
    h2_out[b * 256 + o] = h2h;
  }
  // h1 update: out[o][p] = relu(conv0 + sum_c h1_in[c][p]*r0[o][c] + biases)
  int p = tid & 63;
  int o0 = RL(tid >> 6) * 16;
  int i = p >> 3, j = p & 7;
  const float* xb = x + ((b * 19 + t) * 3) * 576 + (i * 3) * 24 + j * 3;
  float xv[27];
  #pragma unroll
  for (int c = 0; c < 3; ++c)
    #pragma unroll
    for (int ki = 0; ki < 3; ++ki)
      #pragma unroll
      for (int kj = 0; kj < 3; ++kj)
        xv[c * 9 + ki * 3 + kj] = xb[c * 576 + ki * 24 + kj];
  float acc[16];
  #pragma unroll
  for (int q = 0; q < 16; ++q) {
    float a = w0b[o0 + q] + (rec ? r0b[o0 + q] : 0.f);
    const float* wr = w0 + (o0 + q) * 27;   // scalar (uniform) loads
    float c0 = 0, c1 = 0, c2 = 0;
    #pragma unroll
    for (int m = 0; m < 27; m += 3) {
      c0 += xv[m] * wr[m]; c1 += xv[m+1] * wr[m+1]; c2 += xv[m+2] * wr[m+2];
    }
    acc[q] = a + c0 + c1 + c2;
  }
  if (rec) {
    const float* hb = h1_in + b * 4096 + p;
    for (int c = 0; c < 64; c += 4) {
      float h0 = hb[c * 64], h1v = hb[(c+1) * 64], h2v = hb[(c+2) * 64], h3v = hb[(c+3) * 64];
      #pragma unroll
      for (int q = 0; q < 16; ++q) {
        const float* rr = r0 + (o0 + q) * 64 + c;  // scalar loads
        acc[q] += h0 * rr[0] + h1v * rr[1] + h2v * rr[2] + h3v * rr[3];
      }
    }
  }
  float* ob = h1_out + b * 4096 + p;
  #pragma unroll
  for (int q = 0; q < 16; ++q) ob[(o0 + q) * 64] = relu_(acc[q]);
}

// ---------------------------------------------------------------------------
// contract: parts[ks][b][o] = sum_{k in chunk} h1[b][k] * w1T[k][o]
// grid (16 ksplit, 16 btile), 256 threads (o)
// ---------------------------------------------------------------------------
__global__ __launch_bounds__(256) void k_contract(
    const float* __restrict__ h1, const float* __restrict__ w1T,
    float* __restrict__ parts)
{
  int o = threadIdx.x;
  int kc = blockIdx.x * 256;
  int b0 = blockIdx.y * 16;
  float acc[16];
  #pragma unroll
  for (int q = 0; q < 16; ++q) acc[q] = 0.f;
  const float* wp = w1T + kc * 256 + o;
  const float* hp = h1 + b0 * 4096 + kc;
  for (int k = 0; k < 256; k += 4) {
    float w0v = wp[k * 256], w1v = wp[(k+1) * 256], w2v = wp[(k+2) * 256], w3v = wp[(k+3) * 256];
    #pragma unroll
    for (int q = 0; q < 16; ++q) {
      const float* hr = hp + q * 4096 + k;   // scalar s_load_dwordx4
      acc[q] += hr[0] * w0v + hr[1] * w1v + hr[2] * w2v + hr[3] * w3v;
    }
  }
  float* pb = parts + blockIdx.x * 65536 + b0 * 256 + o;
  #pragma unroll
  for (int q = 0; q < 16; ++q) pb[q * 256] = acc[q];
}

// ---------------------------------------------------------------------------
// VQ argmin (one block per b) + fused h2 epilogue for t=18.
// d'[k] = |e_k|^2 - 2 f.e_k  (order-identical to reference distance)
// ---------------------------------------------------------------------------
__global__ __launch_bounds__(256) void k_argmin(
    const float* __restrict__ h1, const float* __restrict__ emb,
    const float* __restrict__ embsq, int* __restrict__ idx,
    const float* __restrict__ parts, const float* __restrict__ w1b,
    const float* __restrict__ linT, const float* __restrict__ linb,
    const float* __restrict__ h2_in, float* __restrict__ h2_out)
{
  int b = blockIdx.x, tid = threadIdx.x;
  {  // h2_18 epilogue
    int o = tid;
    float s = w1b[o];
    const float* pp = parts + b * 256 + o;
    #pragma unroll
    for (int ks = 0; ks < 16; ++ks) s += pp[ks * 65536];
    float h2h = relu_(s);
    const float* h2r = h2_in + b * 256;
    float a0 = 0, a1 = 0;
    for (int jj = 0; jj < 256; jj += 2) {
      a0 += linT[jj * 256 + o] * h2r[jj];
      a1 += linT[(jj + 1) * 256 + o] * h2r[jj + 1];
    }
    h2_out[b * 256 + o] = relu_(h2h + a0 + a1 + linb[o]);
  }
  int p = tid & 63;
  int kg = RL(tid >> 6);
  float f[64];
  const float* hb = h1 + b * 4096 + p;
  #pragma unroll
  for (int c = 0; c < 64; ++c) f[c] = hb[c * 64];
  float best = 3.4e38f; int bk = 0;
  for (int k = kg * 128; k < kg * 128 + 128; ++k) {
    const float* er = emb + k * 64;      // scalar loads (uniform)
    float d0 = 0, d1 = 0, d2 = 0, d3 = 0;
    #pragma unroll
    for (int c = 0; c < 64; c += 4) {
      d0 += f[c] * er[c];   d1 += f[c+1] * er[c+1];
      d2 += f[c+2] * er[c+2]; d3 += f[c+3] * er[c+3];
    }
    float d = embsq[k] - 2.f * ((d0 + d1) + (d2 + d3));
    if (d < best) { best = d; bk = k; }
  }
  __shared__ float sd[256];
  __shared__ int   sk[256];
  sd[tid] = best; sk[tid] = bk;
  __syncthreads();
  if (tid < 64) {
    float bb = sd[tid]; int kk = sk[tid];
    #pragma unroll
    for (int g = 1; g < 4; ++g) {
      float dg = sd[g * 64 + tid];
      if (dg < bb) { bb = dg; kk = sk[g * 64 + tid]; }
    }
    idx[b * 64 + tid] = kk;
  }
}

// ---------------------------------------------------------------------------
// VQ stats: quantized (=emb gather), loss partial, histogram
// ---------------------------------------------------------------------------
__global__ __launch_bounds__(256) void k_stats(
    const float* __restrict__ h1, const float* __restrict__ emb,
    const int* __restrict__ idx, float* __restrict__ Q,
    float* __restrict__ counts, float* __restrict__ loss_sum)
{
  int b = blockIdx.x, tid = threadIdx.x;
  int p = tid & 63, cg = tid >> 6;
  int kk = idx[b * 64 + p];
  const float* eb = emb + kk * 64 + cg * 16;
  const float* hb = h1 + b * 4096 + cg * 1024 + p;
  float* qb = Q + b * 4096 + cg * 1024 + p;
  float ls = 0;
  #pragma unroll
  for (int c = 0; c < 16; ++c) {
    float e = eb[c];
    float z = hb[c * 64];
    float d = e - z;
    ls += d * d;
    qb[c * 64] = e;
  }
  __shared__ float red[256];
  red[tid] = ls; __syncthreads();
  for (int s = 128; s > 0; s >>= 1) { if (tid < s) red[tid] += red[tid + s]; __syncthreads(); }
  if (tid == 0) atomicAdd(loss_sum, red[0]);
  if (tid < 64) atomicAdd(&counts[kk], 1.0f);
}

// ---------------------------------------------------------------------------
// KL + reparam + first decoder lin (h2d0 = relu(dlin @ h2s + b))
// ---------------------------------------------------------------------------
__global__ __launch_bounds__(128) void k_kl(
    const float* __restrict__ h2, const float* __restrict__ eps,
    float* __restrict__ h2s, float* __restrict__ kl_sum,
    const float* __restrict__ dlinT, const float* __restrict__ dlinb,
    float* __restrict__ h2d0)
{
  int b = blockIdx.x, j = threadIdx.x;
  float mu = h2[b * 256 + j];
  float lv = h2[b * 256 + 128 + j];
  float term = 0.5f * (expf(lv) + mu * mu - 1.0f - lv);
  float hs = mu + expf(0.5f * lv) * eps[b * 128 + j];
  h2s[b * 128 + j] = hs;
  __shared__ float sh[128];
  __shared__ float red[128];
  sh[j] = hs; red[j] = term;
  __syncthreads();
  for (int s = 64; s > 0; s >>= 1) { if (j < s) red[j] += red[j + s]; __syncthreads(); }
  if (j == 0) atomicAdd(kl_sum, red[0]);
  float a0 = 0, a1 = 0;
  for (int jj = 0; jj < 128; jj += 2) {
    a0 += dlinT[jj * 128 + j] * sh[jj];
    a1 += dlinT[(jj + 1) * 128 + j] * sh[jj + 1];
  }
  h2d0[b * 128 + j] = relu_(a0 + a1 + dlinb[j]);
}

// ---------------------------------------------------------------------------
// Decoder h1l GEMM: h1l[b][n] = sum_j h2c[b][j] * dw1[j][n]
// grid (16 ntile, 16 btile), 256 threads (n)
// ---------------------------------------------------------------------------
__global__ __launch_bounds__(256) void k_dech1l(
    const float* __restrict__ h2c, const float* __restrict__ dw1,
    float* __restrict__ h1l)
{
  int n = blockIdx.x * 256 + threadIdx.x;
  int b0 = blockIdx.y * 16;
  float acc[16];
  #pragma unroll
  for (int q = 0; q < 16; ++q) acc[q] = 0.f;
  const float* hp = h2c + b0 * 128;
  for (int j = 0; j < 128; j += 4) {
    float w0v = dw1[j * 4096 + n], w1v = dw1[(j+1) * 4096 + n];
    float w2v = dw1[(j+2) * 4096 + n], w3v = dw1[(j+3) * 4096 + n];
    #pragma unroll
    for (int q = 0; q < 16; ++q) {
      const float* hr = hp + q * 128 + j;   // scalar loads
      acc[q] += hr[0] * w0v + hr[1] * w1v + hr[2] * w2v + hr[3] * w3v;
    }
  }
  float* ob = h1l + b0 * 4096 + n;
  #pragma unroll
  for (int q = 0; q < 16; ++q) ob[q * 4096] = acc[q];
}

// ---------------------------------------------------------------------------
// Decoder: h1 recurrence + (optional) ELU frame emit + next-step h2 lin.
// t < 0 -> no emit. One block per b.
// ---------------------------------------------------------------------------
__global__ __launch_bounds__(256) void k_dec_h1out(
    const float* __restrict__ h1_in, const float* __restrict__ h1l,
    const float* __restrict__ dr0, const float* __restrict__ dr0b,
    const float* __restrict__ dw1b, float* __restrict__ h1_out, int t,
    const float* __restrict__ w0d, const float* __restrict__ w0db,
    float* __restrict__ outp,
    const float* __restrict__ h2cur, const float* __restrict__ dlinT,
    const float* __restrict__ dlinb, float* __restrict__ h2next)
{
  __shared__ float h1s[64 * 65];
  int b = blockIdx.x, tid = threadIdx.x;
  int p = tid & 63;
  int o0 = RL(tid >> 6) * 16;
  float acc[16];
  #pragma unroll
  for (int q = 0; q < 16; ++q) acc[q] = dr0b[o0 + q] + dw1b[o0 + q];
  const float* hb = h1_in + b * 4096 + p;
  for (int c = 0; c < 64; c += 4) {
    float h0 = hb[c * 64], h1v = hb[(c+1) * 64], h2v = hb[(c+2) * 64], h3v = hb[(c+3) * 64];
    #pragma unroll
    for (int q = 0; q < 16; ++q) {
      const float* rr = dr0 + (o0 + q) * 64 + c;   // scalar loads
      acc[q] += h0 * rr[0] + h1v * rr[1] + h2v * rr[2] + h3v * rr[3];
    }
  }
  const float* lb = h1l + b * 4096 + p;
  float* ob = h1_out + b * 4096 + p;
  #pragma unroll
  for (int q = 0; q < 16; ++q) {
    float v = relu_(acc[q] + lb[(o0 + q) * 64]);
    ob[(o0 + q) * 64] = v;
    h1s[(o0 + q) * 65 + p] = v;
  }
  __syncthreads();
  if (t >= 0) {
    int mbase = RL((tid >> 6)) * 7;   // m = o3*9 + ki*3 + kj, m < 27
    float a[7];
    #pragma unroll
    for (int qq = 0; qq < 7; ++qq) a[qq] = 0.f;
    for (int c = 0; c < 64; ++c) {
      float hv = h1s[c * 65 + p];
      const float* wr = w0d + c * 27 + mbase;   // scalar loads
      #pragma unroll
      for (int qq = 0; qq < 7; ++qq)
        if (mbase + qq < 27) a[qq] += hv * wr[qq];
    }
    int hrow = p >> 3, wcol = p & 7;
    #pragma unroll
    for (int qq = 0; qq < 7; ++qq) {
      int m = mbase + qq;
      if (m < 27) {
        int o3 = m / 9, r = m % 9, ki = r / 3, kj = r % 3;
        float v = a[qq] + w0db[o3];
        v = v > 0.f ? v : expm1f(v);   // ELU, alpha=1
        outp[2 + ((b * 19 + t) * 3 + o3) * 576 + (hrow * 3 + ki) * 24 + (wcol * 3 + kj)] = v;
      }
    }
  }
  if (tid < 128) {   // h2_{s+1} = relu(dlin @ h2_s + b)
    int o = tid;
    const float* hr = h2cur + b * 128;
    float a0 = 0, a1 = 0;
    for (int jj = 0; jj < 128; jj += 2) {
      a0 += dlinT[jj * 128 + o] * hr[jj];
      a1 += dlinT[(jj + 1) * 128 + o] * hr[jj + 1];
    }
    h2next[b * 128 + o] = relu_(a0 + a1 + dlinb[o]);
  }
}

// ---------------------------------------------------------------------------
// Finalize scalars: loss_vq, kl, perplexity
// ---------------------------------------------------------------------------
__global__ __launch_bounds__(512) void k_finalize(
    const float* __restrict__ counts, const float* __restrict__ scal,
    float* __restrict__ outp)
{
  int tid = threadIdx.x;
  float avg = counts[tid] * (1.0f / 16384.0f);
  float e = avg * logf(avg + 1e-10f);
  __shared__ float red[512];
  red[tid] = e; __syncthreads();
  for (int s = 256; s > 0; s >>= 1) { if (tid < s) red[tid] += red[tid + s]; __syncthreads(); }
  if (tid == 0) {
    outp[0] = 0.25f * scal[0] * (1.0f / 1048576.0f);
    outp[1] = scal[1] * (1.0f / 256.0f);
    outp[2 + 8404992] = expf(-red[0]);
  }
}

// ---------------------------------------------------------------------------
extern "C" void kernel_launch(void* const* d_in, const int* in_sizes, int n_in,
                              void* d_out, int out_size, void* d_ws, size_t ws_size,
                              hipStream_t stream)
{
  const float* x     = (const float*)d_in[0];
  const float* eps   = (const float*)d_in[1];
  const float* emb   = (const float*)d_in[2];
  const float* ew0   = (const float*)d_in[3];
  const float* ew0b  = (const float*)d_in[4];
  const float* ew1   = (const float*)d_in[5];
  const float* ew1b  = (const float*)d_in[6];
  const float* er0   = (const float*)d_in[7];
  const float* er0b  = (const float*)d_in[8];
  const float* elinw = (const float*)d_in[9];
  const float* elinb = (const float*)d_in[10];
  const float* dw0   = (const float*)d_in[11];
  const float* dw0b  = (const float*)d_in[12];
  const float* dw1   = (const float*)d_in[13];
  const float* dw1b  = (const float*)d_in[14];
  const float* dr0   = (const float*)d_in[15];
  const float* dr0b  = (const float*)d_in[16];
  const float* dlinw = (const float*)d_in[17];
  const float* dlinb = (const float*)d_in[18];
  float* out = (float*)d_out;
  float* ws  = (float*)d_ws;

  float* W1T    = ws + 0;        // 4096x256
  float* LINT   = ws + 1048576;  // 256x256 (j-major)
  float* DLINT  = ws + 1114112;  // 128x128 (j-major)
  float* H1A    = ws + 1130496;
  float* H1B    = ws + 2179072;
  float* Q      = ws + 3227648;
  float* H1L    = ws + 4276224;
  float* PARTS  = ws + 5324800;  // 16 x 256 x 256
  float* H2A    = ws + 6373376;
  float* H2B    = ws + 6438912;
  float* H2S    = ws + 6504448;
  float* H2DA   = ws + 6537216;
  float* H2DB   = ws + 6569984;
  float* EMBSQ  = ws + 6602752;
  float* SCAL   = ws + 6603264;  // [0]=loss_sum, [1]=kl_sum
  float* COUNTS = ws + 6603266;  // 512
  int*   IDX    = (int*)(ws + 6603778);  // 16384

  hipMemsetAsync(SCAL, 0, 514 * sizeof(float), stream);
  k_transpose<<<276, 256, 0, stream>>>(ew1, elinw, dlinw, W1T, LINT, DLINT);
  k_embsq<<<2, 256, 0, stream>>>(emb, EMBSQ);

  // ---- encoder: 19 steps; h2 epilogue for step t-1 fused into step t ----
  for (int t = 0; t < 19; ++t) {
    float* h1o = (t & 1) ? H1B : H1A;
    const float* h1i = (t & 1) ? H1A : H1B;
    float* h2o; const float* h2i;
    if ((t - 1) & 1) { h2o = H2B; h2i = H2A; } else { h2o = H2A; h2i = H2B; }
    int ep = (t == 0) ? 0 : ((t == 1) ? 1 : 2);
    k_enc_h1<<<256, 256, 0, stream>>>(x, t, ew0, ew0b, er0, er0b, h1i, h1o,
                                      t > 0 ? 1 : 0, PARTS, ew1b, LINT, elinb,
                                      h2i, h2o, ep);
    k_contract<<<dim3(16, 16), 256, 0, stream>>>(h1o, W1T, PARTS);
  }

  // ---- VQ + KL (h2_18 epilogue fused into argmin; h2d0 fused into kl) ----
  k_argmin<<<256, 256, 0, stream>>>(H1A, emb, EMBSQ, IDX, PARTS, ew1b, LINT,
                                    elinb, H2B, H2A);
  k_stats<<<256, 256, 0, stream>>>(H1A, emb, IDX, Q, COUNTS, &SCAL[0]);
  k_kl<<<256, 128, 0, stream>>>(H2A, eps, H2S, &SCAL[1], DLINT, dlinb, H2DA);

  // ---- decoder: 20 updates, emit frames 0..18 after updates 2..20 ----
  for (int k = 0; k < 20; ++k) {
    const float* h2c = (k & 1) ? H2DB : H2DA;
    float* h2n       = (k & 1) ? H2DA : H2DB;
    const float* h1i = (k == 0) ? Q : ((k & 1) ? H1B : H1A);
    float* h1o       = (k & 1) ? H1A : H1B;
    k_dech1l<<<dim3(16, 16), 256, 0, stream>>>(h2c, dw1, H1L);
    k_dec_h1out<<<256, 256, 0, stream>>>(h1i, H1L, dr0, dr0b, dw1b, h1o, k - 1,
                                         dw0, dw0b, out, h2c, DLINT, dlinb, h2n);
  }

  k_finalize<<<1, 512, 0, stream>>>(COUNTS, SCAL, out);
}

// Round 2
// 1441.695 us; speedup vs baseline: 1.5672x; 1.5672x over previous
//
#include <hip/hip_runtime.h>
#include <math.h>

#define RL(x) __builtin_amdgcn_readfirstlane(x)

__device__ __forceinline__ float relu_(float v) { return v > 0.f ? v : 0.f; }

// ---------------------------------------------------------------------------
// One-time prep: transposes of enc_w1 [256x4096], enc_lin_w [256x256],
// dec_lin_w [128x128] (out[c*R+r] = in[r*C+c]) + |emb_k|^2.
// ---------------------------------------------------------------------------
__global__ __launch_bounds__(256) void k_prep(
    const float* __restrict__ w1, const float* __restrict__ linw,
    const float* __restrict__ dlinw, const float* __restrict__ emb,
    float* __restrict__ w1T, float* __restrict__ linT,
    float* __restrict__ dlinT, float* __restrict__ embsq)
{
  int bid = blockIdx.x;
  if (bid >= 276) {  // embsq: bid 276,277 -> 512 codes
    int k = (bid - 276) * 256 + threadIdx.x;
    const float* e = emb + k * 64;
    float s0 = 0, s1 = 0, s2 = 0, s3 = 0;
    #pragma unroll
    for (int c = 0; c < 64; c += 4) {
      s0 += e[c] * e[c]; s1 += e[c+1] * e[c+1];
      s2 += e[c+2] * e[c+2]; s3 += e[c+3] * e[c+3];
    }
    embsq[k] = (s0 + s1) + (s2 + s3);
    return;
  }
  __shared__ float buf[64 * 65];
  const float* in; float* out; int R, C, tr, tc;
  if (bid < 256)      { in = w1;    out = w1T;   R = 256; C = 4096; tr = bid >> 6;         tc = bid & 63; }
  else if (bid < 272) { in = linw;  out = linT;  R = 256; C = 256;  tr = (bid - 256) >> 2; tc = (bid - 256) & 3; }
  else                { in = dlinw; out = dlinT; R = 128; C = 128;  tr = (bid - 272) >> 1; tc = (bid - 272) & 1; }
  int r0 = tr * 64, c0 = tc * 64;
  int lane = threadIdx.x & 63, grp = threadIdx.x >> 6;
  for (int pp = 0; pp < 16; ++pp) {
    int rr = pp * 4 + grp;
    buf[rr * 65 + lane] = in[(r0 + rr) * C + c0 + lane];
  }
  __syncthreads();
  for (int pp = 0; pp < 16; ++pp) {
    int cc = pp * 4 + grp;
    out[(c0 + cc) * R + r0 + lane] = buf[lane * 65 + cc];
  }
}

// ---------------------------------------------------------------------------
// Encoder pipeline step E_t (t=0..19), grid 512:
//  blocks 0..255   (b=bid):  h2_{t-2} epilogue (t>=2) + h1_t recurrence (t<=18)
//  blocks 256..511        :  contract_{t-1} split-K GEMM from h1_{t-1} (t>=1)
// All inputs were produced by kernel E_{t-1} (or earlier) -> both halves
// run concurrently with no intra-kernel dependence.
// ---------------------------------------------------------------------------
__global__ __launch_bounds__(256) void k_enc(
    const float* __restrict__ x, int t,
    const float* __restrict__ w0, const float* __restrict__ w0b,
    const float* __restrict__ r0, const float* __restrict__ r0b,
    const float* __restrict__ h1_in, float* __restrict__ h1_out,
    const float* __restrict__ w1T, float* __restrict__ parts_out,
    const float* __restrict__ parts_in, const float* __restrict__ w1b,
    const float* __restrict__ linT, const float* __restrict__ linb,
    const float* __restrict__ h2_in, float* __restrict__ h2_out)
{
  int bid = blockIdx.x, tid = threadIdx.x;
  if (bid >= 256) {           // ---- contract_{t-1} half ----
    if (t == 0) return;
    int cid = bid - 256;
    int kc = (cid & 15) * 256;
    int b0 = (cid >> 4) * 16;
    float acc[16];
    #pragma unroll
    for (int q = 0; q < 16; ++q) acc[q] = 0.f;
    const float* wp = w1T + kc * 256 + tid;
    const float* hp = h1_in + b0 * 4096 + kc;
    for (int k = 0; k < 256; k += 4) {
      float w0v = wp[k * 256], w1v = wp[(k+1) * 256], w2v = wp[(k+2) * 256], w3v = wp[(k+3) * 256];
      #pragma unroll
      for (int q = 0; q < 16; ++q) {
        const float* hr = hp + q * 4096 + k;   // thread-uniform -> s_load
        acc[q] += hr[0] * w0v + hr[1] * w1v + hr[2] * w2v + hr[3] * w3v;
      }
    }
    float* pb = parts_out + (cid & 15) * 65536 + b0 * 256 + tid;
    #pragma unroll
    for (int q = 0; q < 16; ++q) pb[q * 256] = acc[q];
    return;
  }
  int b = bid;
  if (t >= 2) {               // ---- h2_{t-2} epilogue ----
    int o = tid;
    float s = w1b[o];
    const float* pp = parts_in + b * 256 + o;
    #pragma unroll
    for (int ks = 0; ks < 16; ++ks) s += pp[ks * 65536];
    float h2h = relu_(s);
    if (t >= 3) {             // lin recurrence with h2_{t-3}
      const float* h2r = h2_in + b * 256;
      float a0 = 0, a1 = 0;
      for (int j = 0; j < 256; j += 2) {
        a0 += linT[j * 256 + o] * h2r[j];
        a1 += linT[(j + 1) * 256 + o] * h2r[j + 1];
      }
      h2h = relu_(h2h + a0 + a1 + linb[o]);
    }
    h2_out[b * 256 + o] = h2h;
  }
  if (t > 18) return;
  // ---- h1_t = relu(conv0(x_t) [+ r0 . h1_{t-1} + r0b]) ----
  int p = tid & 63;
  int o0 = RL(tid >> 6) * 16;
  int i = p >> 3, j = p & 7;
  const float* xb = x + ((b * 19 + t) * 3) * 576 + (i * 3) * 24 + j * 3;
  float xv[27];
  #pragma unroll
  for (int c = 0; c < 3; ++c)
    #pragma unroll
    for (int ki = 0; ki < 3; ++ki)
      #pragma unroll
      for (int kj = 0; kj < 3; ++kj)
        xv[c * 9 + ki * 3 + kj] = xb[c * 576 + ki * 24 + kj];
  float acc[16];
  #pragma unroll
  for (int q = 0; q < 16; ++q) {
    float a = w0b[o0 + q] + (t > 0 ? r0b[o0 + q] : 0.f);
    const float* wr = w0 + (o0 + q) * 27;   // uniform -> s_load
    float c0 = 0, c1 = 0, c2 = 0;
    #pragma unroll
    for (int m = 0; m < 27; m += 3) {
      c0 += xv[m] * wr[m]; c1 += xv[m+1] * wr[m+1]; c2 += xv[m+2] * wr[m+2];
    }
    acc[q] = a + c0 + c1 + c2;
  }
  if (t > 0) {
    const float* hb = h1_in + b * 4096 + p;
    for (int c = 0; c < 64; c += 4) {
      float h0 = hb[c * 64], h1v = hb[(c+1) * 64], h2v = hb[(c+2) * 64], h3v = hb[(c+3) * 64];
      #pragma unroll
      for (int q = 0; q < 16; ++q) {
        const float* rr = r0 + (o0 + q) * 64 + c;  // uniform -> s_load
        acc[q] += h0 * rr[0] + h1v * rr[1] + h2v * rr[2] + h3v * rr[3];
      }
    }
  }
  float* ob = h1_out + b * 4096 + p;
  #pragma unroll
  for (int q = 0; q < 16; ++q) ob[(o0 + q) * 64] = relu_(acc[q]);
}

// ---------------------------------------------------------------------------
// VQ argmin + h2_18 epilogue + VQ stats (Q gather, loss, LDS histogram).
// One block per b. d'[k] = |e_k|^2 - 2 f.e_k (order == reference distance).
// ---------------------------------------------------------------------------
__global__ __launch_bounds__(256) void k_argmin(
    const float* __restrict__ h1, const float* __restrict__ emb,
    const float* __restrict__ embsq,
    const float* __restrict__ parts, const float* __restrict__ w1b,
    const float* __restrict__ linT, const float* __restrict__ linb,
    const float* __restrict__ h2_in, float* __restrict__ h2_out,
    float* __restrict__ Q, float* __restrict__ counts,
    float* __restrict__ loss_sum)
{
  __shared__ float sd[256];
  __shared__ int   sk[256];
  __shared__ int   fk[64];
  __shared__ int   lhist[512];
  __shared__ float red[256];
  int b = blockIdx.x, tid = threadIdx.x;
  {  // ---- h2_18 epilogue ----
    int o = tid;
    float s = w1b[o];
    const float* pp = parts + b * 256 + o;
    #pragma unroll
    for (int ks = 0; ks < 16; ++ks) s += pp[ks * 65536];
    float h2h = relu_(s);
    const float* h2r = h2_in + b * 256;
    float a0 = 0, a1 = 0;
    for (int jj = 0; jj < 256; jj += 2) {
      a0 += linT[jj * 256 + o] * h2r[jj];
      a1 += linT[(jj + 1) * 256 + o] * h2r[jj + 1];
    }
    h2_out[b * 256 + o] = relu_(h2h + a0 + a1 + linb[o]);
  }
  // ---- argmin over K=512 (4 wave-groups x 128 codes) ----
  int p = tid & 63;
  int kg = RL(tid >> 6);
  float f[64];
  const float* hb = h1 + b * 4096 + p;
  #pragma unroll
  for (int c = 0; c < 64; ++c) f[c] = hb[c * 64];
  float best = 3.4e38f; int bk = 0;
  for (int k = kg * 128; k < kg * 128 + 128; ++k) {
    const float* er = emb + k * 64;      // uniform -> s_load
    float d0 = 0, d1 = 0, d2 = 0, d3 = 0;
    #pragma unroll
    for (int c = 0; c < 64; c += 4) {
      d0 += f[c] * er[c];     d1 += f[c+1] * er[c+1];
      d2 += f[c+2] * er[c+2]; d3 += f[c+3] * er[c+3];
    }
    float d = embsq[k] - 2.f * ((d0 + d1) + (d2 + d3));
    if (d < best) { best = d; bk = k; }
  }
  sd[tid] = best; sk[tid] = bk;
  for (int jj = tid; jj < 512; jj += 256) lhist[jj] = 0;
  __syncthreads();
  if (tid < 64) {
    float bb = sd[tid]; int kk = sk[tid];
    #pragma unroll
    for (int g = 1; g < 4; ++g) {
      float dg = sd[g * 64 + tid];
      if (dg < bb) { bb = dg; kk = sk[g * 64 + tid]; }
    }
    fk[tid] = kk;
    atomicAdd(&lhist[kk], 1);   // LDS histogram
  }
  __syncthreads();
  // ---- stats: Q gather + commitment-loss partial ----
  int cg = tid >> 6;
  int kk = fk[p];
  const float* eb = emb + kk * 64 + cg * 16;
  const float* hz = h1 + b * 4096 + cg * 1024 + p;
  float* qb = Q + b * 4096 + cg * 1024 + p;
  float ls = 0;
  #pragma unroll
  for (int c = 0; c < 16; ++c) {
    float e = eb[c];
    float z = hz[c * 64];
    float d = e - z;
    ls += d * d;
    qb[c * 64] = e;
  }
  red[tid] = ls;
  __syncthreads();
  for (int s = 128; s > 0; s >>= 1) { if (tid < s) red[tid] += red[tid + s]; __syncthreads(); }
  if (tid == 0) atomicAdd(loss_sum, red[0]);
  // flush only nonzero histogram bins (aggregated -> low atomic contention)
  for (int jj = tid; jj < 512; jj += 256) {
    int h = lhist[jj];
    if (h > 0) atomicAdd(&counts[jj], (float)h);
  }
}

// ---------------------------------------------------------------------------
// KL + reparam + the ENTIRE decoder h2 chain (depends only on itself):
// h2_0 = relu(dlin.h2s + b); h2_{s+1} = relu(dlin.h2_s + b); s = 0..19.
// ---------------------------------------------------------------------------
__global__ __launch_bounds__(128) void k_h2chain(
    const float* __restrict__ h2, const float* __restrict__ eps,
    float* __restrict__ kl_sum,
    const float* __restrict__ dlinT, const float* __restrict__ dlinb,
    float* __restrict__ h2all)
{
  __shared__ float cur[128];
  __shared__ float red[128];
  int b = blockIdx.x, j = threadIdx.x;
  float mu = h2[b * 256 + j];
  float lv = h2[b * 256 + 128 + j];
  float term = 0.5f * (expf(lv) + mu * mu - 1.0f - lv);
  float hs = mu + expf(0.5f * lv) * eps[b * 128 + j];
  red[j] = term; cur[j] = hs;
  __syncthreads();
  for (int s = 64; s > 0; s >>= 1) { if (j < s) red[j] += red[j + s]; __syncthreads(); }
  if (j == 0) atomicAdd(kl_sum, red[0]);
  for (int s = 0; s < 20; ++s) {
    float a0 = 0, a1 = 0;
    for (int jj = 0; jj < 128; jj += 2) {
      a0 += dlinT[jj * 128 + j] * cur[jj];
      a1 += dlinT[(jj + 1) * 128 + j] * cur[jj + 1];
    }
    float v = relu_(a0 + a1 + dlinb[j]);
    h2all[s * 32768 + b * 128 + j] = v;
    __syncthreads();
    cur[j] = v;
    __syncthreads();
  }
}

// ---------------------------------------------------------------------------
// Decoder pipeline step D_k (k=0..20), grid 512:
//  blocks 0..255  (b=bid): h1_{k-1} = relu(dr0.h1_{k-2} + h1l_{k-1} + biases)
//                          + ELU frame emit (frame k-2, for k>=2)
//  blocks 256..511       : h1l_k = h2all[k] @ dw1 (b-tiled GEMM, k<=19)
// ---------------------------------------------------------------------------
__global__ __launch_bounds__(256) void k_dec(
    int k, const float* __restrict__ h2all, const float* __restrict__ dw1,
    float* __restrict__ h1l_out,
    const float* __restrict__ h1_in, const float* __restrict__ h1l_in,
    const float* __restrict__ dr0, const float* __restrict__ dr0b,
    const float* __restrict__ dw1b, float* __restrict__ h1_out,
    const float* __restrict__ w0d, const float* __restrict__ w0db,
    float* __restrict__ outp)
{
  int bid = blockIdx.x, tid = threadIdx.x;
  if (bid >= 256) {           // ---- h1l_k GEMM half ----
    if (k > 19) return;
    int cid = bid - 256;
    int n = (cid & 15) * 256 + tid;
    int b0 = (cid >> 4) * 16;
    float acc[16];
    #pragma unroll
    for (int q = 0; q < 16; ++q) acc[q] = 0.f;
    const float* hp = h2all + k * 32768 + b0 * 128;
    for (int j = 0; j < 128; j += 4) {
      float w0v = dw1[j * 4096 + n], w1v = dw1[(j+1) * 4096 + n];
      float w2v = dw1[(j+2) * 4096 + n], w3v = dw1[(j+3) * 4096 + n];
      #pragma unroll
      for (int q = 0; q < 16; ++q) {
        const float* hr = hp + q * 128 + j;   // uniform -> s_load
        acc[q] += hr[0] * w0v + hr[1] * w1v + hr[2] * w2v + hr[3] * w3v;
      }
    }
    float* ob = h1l_out + b0 * 4096 + n;
    #pragma unroll
    for (int q = 0; q < 16; ++q) ob[q * 4096] = acc[q];
    return;
  }
  if (k == 0) return;
  // ---- h1 recurrence half ----
  __shared__ float h1s[64 * 65];
  int b = bid;
  int p = tid & 63;
  int o0 = RL(tid >> 6) * 16;
  float acc[16];
  #pragma unroll
  for (int q = 0; q < 16; ++q) acc[q] = dr0b[o0 + q] + dw1b[o0 + q];
  const float* hb = h1_in + b * 4096 + p;
  for (int c = 0; c < 64; c += 4) {
    float h0 = hb[c * 64], h1v = hb[(c+1) * 64], h2v = hb[(c+2) * 64], h3v = hb[(c+3) * 64];
    #pragma unroll
    for (int q = 0; q < 16; ++q) {
      const float* rr = dr0 + (o0 + q) * 64 + c;   // uniform -> s_load
      acc[q] += h0 * rr[0] + h1v * rr[1] + h2v * rr[2] + h3v * rr[3];
    }
  }
  const float* lb = h1l_in + b * 4096 + p;
  float* ob = h1_out + b * 4096 + p;
  #pragma unroll
  for (int q = 0; q < 16; ++q) {
    float v = relu_(acc[q] + lb[(o0 + q) * 64]);
    ob[(o0 + q) * 64] = v;
    h1s[(o0 + q) * 65 + p] = v;
  }
  __syncthreads();
  int t = k - 2;              // frame index
  if (t >= 0) {
    int mbase = RL(tid >> 6) * 7;   // m = o3*9 + ki*3 + kj (< 27)
    float a[7];
    #pragma unroll
    for (int qq = 0; qq < 7; ++qq) a[qq] = 0.f;
    for (int c = 0; c < 64; ++c) {
      float hv = h1s[c * 65 + p];
      const float* wr = w0d + c * 27 + mbase;   // uniform -> s_load
      #pragma unroll
      for (int qq = 0; qq < 7; ++qq)
        if (mbase + qq < 27) a[qq] += hv * wr[qq];
    }
    int hrow = p >> 3, wcol = p & 7;
    #pragma unroll
    for (int qq = 0; qq < 7; ++qq) {
      int m = mbase + qq;
      if (m < 27) {
        int o3 = m / 9, r = m % 9, ki = r / 3, kj = r % 3;
        float v = a[qq] + w0db[o3];
        v = v > 0.f ? v : expm1f(v);   // ELU alpha=1
        outp[2 + ((b * 19 + t) * 3 + o3) * 576 + (hrow * 3 + ki) * 24 + (wcol * 3 + kj)] = v;
      }
    }
  }
}

// ---------------------------------------------------------------------------
// Finalize scalars: loss_vq, kl, perplexity
// ---------------------------------------------------------------------------
__global__ __launch_bounds__(512) void k_finalize(
    const float* __restrict__ counts, const float* __restrict__ scal,
    float* __restrict__ outp)
{
  int tid = threadIdx.x;
  float avg = counts[tid] * (1.0f / 16384.0f);
  float e = avg * logf(avg + 1e-10f);
  __shared__ float red[512];
  red[tid] = e; __syncthreads();
  for (int s = 256; s > 0; s >>= 1) { if (tid < s) red[tid] += red[tid + s]; __syncthreads(); }
  if (tid == 0) {
    outp[0] = 0.25f * scal[0] * (1.0f / 1048576.0f);
    outp[1] = scal[1] * (1.0f / 256.0f);
    outp[2 + 8404992] = expf(-red[0]);
  }
}

// ---------------------------------------------------------------------------
extern "C" void kernel_launch(void* const* d_in, const int* in_sizes, int n_in,
                              void* d_out, int out_size, void* d_ws, size_t ws_size,
                              hipStream_t stream)
{
  const float* x     = (const float*)d_in[0];
  const float* eps   = (const float*)d_in[1];
  const float* emb   = (const float*)d_in[2];
  const float* ew0   = (const float*)d_in[3];
  const float* ew0b  = (const float*)d_in[4];
  const float* ew1   = (const float*)d_in[5];
  const float* ew1b  = (const float*)d_in[6];
  const float* er0   = (const float*)d_in[7];
  const float* er0b  = (const float*)d_in[8];
  const float* elinw = (const float*)d_in[9];
  const float* elinb = (const float*)d_in[10];
  const float* dw0   = (const float*)d_in[11];
  const float* dw0b  = (const float*)d_in[12];
  const float* dw1   = (const float*)d_in[13];
  const float* dw1b  = (const float*)d_in[14];
  const float* dr0   = (const float*)d_in[15];
  const float* dr0b  = (const float*)d_in[16];
  const float* dlinw = (const float*)d_in[17];
  const float* dlinb = (const float*)d_in[18];
  float* out = (float*)d_out;
  float* ws  = (float*)d_ws;

  // ---- workspace layout (floats). H2ALL overlays W1T (encoder-only);
  //      H1L0/H1L1 overlay PARTS0/PARTS1 (encoder-only). Total 26.0 MB. ----
  float* W1T    = ws + 0;        // 4096x256 (encoder)
  float* H2ALL  = ws + 0;        // 20x256x128 (decoder; after last W1T use)
  float* LINT   = ws + 1048576;  // 256x256
  float* DLINT  = ws + 1114112;  // 128x128
  float* EMBSQ  = ws + 1130496;  // 512
  float* H1A    = ws + 1131008;  // 256x4096 (h1 state, parity 0)
  float* H1B    = ws + 2179584;  // 256x4096 (h1 state, parity 1)
  float* Q      = ws + 3228160;  // 256x4096 quantized
  float* PARTS0 = ws + 4276736;  // 16x256x256 (contract parity 0)
  float* PARTS1 = ws + 5325312;  // 16x256x256 (contract parity 1)
  float* H1L0   = PARTS0;        // decoder h1l parity 0 (overlay)
  float* H1L1   = PARTS1;        // decoder h1l parity 1 (overlay)
  float* H2A    = ws + 6373888;  // 256x256 (enc h2, parity 0)
  float* H2B    = ws + 6439424;  // 256x256 (enc h2, parity 1)
  float* SCAL   = ws + 6504960;  // [0]=loss_sum, [1]=kl_sum
  float* COUNTS = ws + 6504962;  // 512

  hipMemsetAsync(SCAL, 0, 514 * sizeof(float), stream);
  k_prep<<<278, 256, 0, stream>>>(ew1, elinw, dlinw, emb, W1T, LINT, DLINT, EMBSQ);

  // ---- encoder pipeline: E_t computes h1_t, contract_{t-1}, h2_{t-2} ----
  // buffer parities: h1_s -> s&1 (0=H1A); contract_s -> s&1; h2_s -> s&1 (0=H2A)
  for (int t = 0; t < 20; ++t) {
    const float* h1i = (t & 1) ? H1A : H1B;          // h1_{t-1}
    float* h1o       = (t & 1) ? H1B : H1A;          // h1_t
    float* po        = ((t - 1) & 1) ? PARTS1 : PARTS0;  // contract_{t-1}
    const float* pi  = (t & 1) ? PARTS1 : PARTS0;        // contract_{t-2}
    float* h2o       = (t & 1) ? H2B : H2A;          // h2_{t-2}
    const float* h2i = (t & 1) ? H2A : H2B;          // h2_{t-3}
    k_enc<<<512, 256, 0, stream>>>(x, t, ew0, ew0b, er0, er0b, h1i, h1o,
                                   W1T, po, pi, ew1b, LINT, elinb, h2i, h2o);
  }

  // ---- VQ (+h2_18 epilogue, stats fused) ----
  k_argmin<<<256, 256, 0, stream>>>(H1A, emb, EMBSQ, PARTS0, ew1b, LINT, elinb,
                                    H2B, H2A, Q, COUNTS, &SCAL[0]);
  // ---- KL + full decoder h2 chain ----
  k_h2chain<<<256, 128, 0, stream>>>(H2A, eps, &SCAL[1], DLINT, dlinb, H2ALL);

  // ---- decoder pipeline: D_k computes h1_{k-1} (+frame k-2) and h1l_k ----
  for (int k = 0; k <= 20; ++k) {
    int s = k - 1;                                   // h1 state index
    float* h1l_o      = (k & 1) ? H1L1 : H1L0;       // h1l_k
    const float* h1l_i = (k & 1) ? H1L0 : H1L1;      // h1l_{k-1}
    const float* h1i  = (s <= 0) ? Q : (((s - 1) & 1) ? H1B : H1A);
    float* h1o        = (s >= 0 && (s & 1)) ? H1B : H1A;
    k_dec<<<512, 256, 0, stream>>>(k, H2ALL, dw1, h1l_o, h1i, h1l_i,
                                   dr0, dr0b, dw1b, h1o, dw0, dw0b, out);
  }

  k_finalize<<<1, 512, 0, stream>>>(COUNTS, SCAL, out);
}